// Round 10
// baseline (9119.650 us; speedup 1.0000x reference)
//
#include <hip/hip_runtime.h>
#include <hip/hip_bf16.h>
#include <stdint.h>

// GRU fused scan: B=128, T=512, I=H=512.
// 256 wgs x 192 threads (3 waves = gates r,z,n). wg (bgrp=id&7, ugrp=id>>3)
// owns batch rows [bgrp*16,+16) and hidden units [ugrp*16,+16).
// FAST path (ws_size >= 512KB): tagged-data sync. h[t] published as u32 words
// {tag16=t | bf16 payload} into a ring-2 buffer th[2][128][512]. Producers
// store-and-go (NO vmcnt drain, NO flag). Consumers tag-poll the data words
// themselves (retry until all 128 tags == t) -> discovery + data in ONE
// round trip instead of r6's three (publish-ack, flag hop, h-load).
// WAR safety: publishing h[t+1] requires having tag-validated ALL of h[t],
// which by data-dependence proves all wgs' h[t-1] reads completed -> slot
// (t+1)&1 is dead. memset(0) = valid tagged h[0]=0 in slot 0.
// Per-wave redundant h loads kept (r9 proved de-dup serialization hurts).
// FALLBACK path (small ws): round-6 kernel verbatim (proven, 257KB).

static constexpr int INPUT = 512;
static constexpr int HID   = 512;
static constexpr int NB    = 128;
static constexpr int TLEN  = 512;
static constexpr int BGRPS = 8;
static constexpr int UGRPS = 32;

typedef __attribute__((ext_vector_type(4))) float f32x4;
typedef __attribute__((ext_vector_type(8))) short s16x8;

static __device__ __forceinline__ unsigned short f2bf(float f) {
  unsigned u = __builtin_bit_cast(unsigned, f);
  u += 0x7FFFu + ((u >> 16) & 1u);   // RNE
  return (unsigned short)(u >> 16);
}

// 8 consecutive fp32 -> bf16x8 (RNE via packed convert)
static __device__ __forceinline__ s16x8 cvt8(const float* p) {
  f32x4 a = *(const f32x4*)p;
  f32x4 b = *(const f32x4*)(p + 4);
  unsigned r0, r1, r2, r3;
  asm("v_cvt_pk_bf16_f32 %0, %1, %2" : "=v"(r0) : "v"(a[0]), "v"(a[1]));
  asm("v_cvt_pk_bf16_f32 %0, %1, %2" : "=v"(r1) : "v"(a[2]), "v"(a[3]));
  asm("v_cvt_pk_bf16_f32 %0, %1, %2" : "=v"(r2) : "v"(b[0]), "v"(b[1]));
  asm("v_cvt_pk_bf16_f32 %0, %1, %2" : "=v"(r3) : "v"(b[2]), "v"(b[3]));
  union { unsigned u[4]; s16x8 s; } r;
  r.u[0] = r0; r.u[1] = r1; r.u[2] = r2; r.u[3] = r3;
  return r.s;
}

// ============================ FAST: tagged protocol ============================

__global__ __launch_bounds__(192, 1) void gru_tagged(
    const float* __restrict__ xs, const float* __restrict__ wih,
    const float* __restrict__ whh, const float* __restrict__ bias,
    const float* __restrict__ bias_n, float* __restrict__ out,
    unsigned int* __restrict__ th)   // [2][NB][HID] tagged h words
{
  const int wg   = blockIdx.x;
  const int bgrp = wg & 7;
  const int ugrp = wg >> 3;
  const int b0   = bgrp * 16;
  const int u0   = ugrp * 16;
  const int tid  = threadIdx.x;
  const int g    = tid >> 6;      // 0=r, 1=z, 2=n
  const int lane = tid & 63;
  const int ln   = lane & 15;     // unit / batch-row index within tile
  const int kg   = lane >> 4;     // k-octet group 0..3

  __shared__ float xch[2][4][16][16];   // dbuf gate exchange

  // ---- preload weight fragments into registers (one-time) ----
  const int rowW = g * HID + u0 + ln;
  s16x8 wa[16], wb[16];
#pragma unroll
  for (int ks = 0; ks < 16; ++ks) {
    const int k = ks * 32 + kg * 8;
    wa[ks] = cvt8(wih + (size_t)rowW * INPUT + k);
    wb[ks] = cvt8(whh + (size_t)rowW * HID + k);
  }
  const float bv = bias[rowW];
  const float bn = bias_n[u0 + ln];

  const float* xrow = xrow = xs + (size_t)(b0 + ln) * TLEN * INPUT + kg * 8;

  float hold[4] = {0.f, 0.f, 0.f, 0.f};

  // ---- prologue: input-side GEMM for t = 0 ----
  f32x4 acc_a = {bv, bv, bv, bv};
#pragma unroll
  for (int ks = 0; ks < 16; ++ks) {
    s16x8 xa = cvt8(xrow + ks * 32);
    acc_a = __builtin_amdgcn_mfma_f32_16x16x32_bf16(xa, wa[ks], acc_a, 0, 0, 0);
  }

  for (int t = 0; t < TLEN; ++t) {
    // ---- tagged retry-load of h[t]: data IS the flag ----
    const unsigned* hb = th + (size_t)(t & 1) * (NB * HID) + (b0 + ln) * HID + kg * 8;
    const unsigned expv = (unsigned)t << 16;
    unsigned w[16][8];
    while (true) {
#pragma unroll
      for (int c = 0; c < 16; ++c)
#pragma unroll
        for (int j = 0; j < 8; ++j)
          w[c][j] = __hip_atomic_load(hb + c * 32 + j,
                                      __ATOMIC_RELAXED, __HIP_MEMORY_SCOPE_AGENT);
      unsigned a0 = 0, a1 = 0, a2 = 0, a3 = 0;
#pragma unroll
      for (int c = 0; c < 16; c += 4)
#pragma unroll
        for (int j = 0; j < 8; ++j) {
          a0 |= (w[c    ][j] ^ expv) & 0xffff0000u;
          a1 |= (w[c + 1][j] ^ expv) & 0xffff0000u;
          a2 |= (w[c + 2][j] ^ expv) & 0xffff0000u;
          a3 |= (w[c + 3][j] ^ expv) & 0xffff0000u;
        }
      if (__ballot(((a0 | a1) | (a2 | a3)) != 0) == 0) break;
    }
    __builtin_amdgcn_sched_barrier(0);

    // ---- recurrent GEMM: pack payloads -> bf16 frags -> MFMA ----
    f32x4 acc_b0 = {0.f, 0.f, 0.f, 0.f}, acc_b1 = {0.f, 0.f, 0.f, 0.f};
#pragma unroll
    for (int c = 0; c < 16; c += 2) {
      union { unsigned u[4]; s16x8 s; } fa, fb;
#pragma unroll
      for (int q = 0; q < 4; ++q) {
        fa.u[q] = __builtin_amdgcn_perm(w[c    ][2 * q + 1], w[c    ][2 * q], 0x05040100u);
        fb.u[q] = __builtin_amdgcn_perm(w[c + 1][2 * q + 1], w[c + 1][2 * q], 0x05040100u);
      }
      acc_b0 = __builtin_amdgcn_mfma_f32_16x16x32_bf16(fa.s, wb[c],     acc_b0, 0, 0, 0);
      acc_b1 = __builtin_amdgcn_mfma_f32_16x16x32_bf16(fb.s, wb[c + 1], acc_b1, 0, 0, 0);
    }
    f32x4 acc_b = acc_b0 + acc_b1;

    // ---- exchange gate pre-activations across the 3 waves (dbuf LDS) ----
    float (*xc)[16][16] = xch[t & 1];
    if (g == 0)      { f32x4 s = acc_a + acc_b; *(f32x4*)&xc[0][ln][kg * 4] = s; }
    else if (g == 1) { f32x4 s = acc_a + acc_b; *(f32x4*)&xc[1][ln][kg * 4] = s; }
    else             { *(f32x4*)&xc[2][ln][kg * 4] = acc_a;
                       *(f32x4*)&xc[3][ln][kg * 4] = acc_b; }
    __syncthreads();
    f32x4 Sr  = *(const f32x4*)&xc[0][ln][kg * 4];
    f32x4 Sz  = *(const f32x4*)&xc[1][ln][kg * 4];
    f32x4 Snx = *(const f32x4*)&xc[2][ln][kg * 4];
    f32x4 Snh = *(const f32x4*)&xc[3][ln][kg * 4];

    // ---- gate math ----
    float hnew[4];
#pragma unroll
    for (int i = 0; i < 4; ++i) {
      float r = 1.f / (1.f + __expf(-Sr[i]));
      float z = 1.f / (1.f + __expf(-Sz[i]));
      float pre = Snx[i] + r * (Snh[i] + bn);
      float e = __expf(2.f * pre);
      float n = 1.f - 2.f / (e + 1.f);   // tanh, overflow-safe
      hnew[i] = n + z * (hold[i] - n);
      hold[i] = hnew[i];
    }

    if (t == TLEN - 1) {
      if (g == 0) {
#pragma unroll
        for (int i = 0; i < 4; ++i)
          out[(size_t)(b0 + kg * 4 + i) * HID + u0 + ln] = hnew[i];
      }
    } else {
      // ---- publish h[t+1] as tagged words: store-and-go ----
      if (g == 0) {
        unsigned* thn = th + (size_t)((t + 1) & 1) * (NB * HID);
        const unsigned tg = (unsigned)(t + 1) << 16;
#pragma unroll
        for (int i = 0; i < 4; ++i) {
          unsigned wv = tg | (unsigned)f2bf(hnew[i]);
          __hip_atomic_store(thn + (size_t)(b0 + kg * 4 + i) * HID + (u0 + ln), wv,
                             __ATOMIC_RELAXED, __HIP_MEMORY_SCOPE_AGENT);
        }
      }

      // ---- input-side GEMM for step t+1 (overlaps store propagation) ----
      acc_a = (f32x4){bv, bv, bv, bv};
      const float* xp = xrow + (size_t)(t + 1) * INPUT;
#pragma unroll
      for (int ks = 0; ks < 16; ++ks) {
        s16x8 xa = cvt8(xp + ks * 32);
        acc_a = __builtin_amdgcn_mfma_f32_16x16x32_bf16(xa, wa[ks], acc_a, 0, 0, 0);
      }
    }
  }
}

// ===================== FALLBACK: round-6 proven kernel =====================

__global__ __launch_bounds__(192, 2) void gru_flag(
    const float* __restrict__ xs, const float* __restrict__ wih,
    const float* __restrict__ whh, const float* __restrict__ bias,
    const float* __restrict__ bias_n, float* __restrict__ out,
    unsigned short* __restrict__ hbuf, unsigned int* __restrict__ flags)
{
  const int wg   = blockIdx.x;
  const int bgrp = wg & 7;
  const int ugrp = wg >> 3;
  const int b0   = bgrp * 16;
  const int u0   = ugrp * 16;
  const int tid  = threadIdx.x;
  const int g    = tid >> 6;
  const int lane = tid & 63;
  const int ln   = lane & 15;
  const int kg   = lane >> 4;

  const int rowW = g * HID + u0 + ln;
  s16x8 wa[16], wb[16];
#pragma unroll
  for (int ks = 0; ks < 16; ++ks) {
    const int k = ks * 32 + kg * 8;
    wa[ks] = cvt8(wih + (size_t)rowW * INPUT + k);
    wb[ks] = cvt8(whh + (size_t)rowW * HID + k);
  }
  const float bv = bias[rowW];
  const float bn = bias_n[u0 + ln];

  const float* xrow = xs + (size_t)(b0 + ln) * TLEN * INPUT + kg * 8;
  const int hoff = (b0 + ln) * HID + kg * 8;

  __shared__ float xch[2][4][16][16];
  float hold[4] = {0.f, 0.f, 0.f, 0.f};

  f32x4 acc_a = {bv, bv, bv, bv};
#pragma unroll
  for (int ks = 0; ks < 16; ++ks) {
    s16x8 xa = cvt8(xrow + ks * 32);
    acc_a = __builtin_amdgcn_mfma_f32_16x16x32_bf16(xa, wa[ks], acc_a, 0, 0, 0);
  }

  for (int t = 0; t < TLEN; ++t) {
    if (t > 0) {
      const unsigned* fp = &flags[bgrp * UGRPS + (lane & 31)];
      unsigned fv;
      do {
        fv = __hip_atomic_load(fp, __ATOMIC_RELAXED, __HIP_MEMORY_SCOPE_AGENT);
      } while (~__ballot(fv >= (unsigned)t));
      __builtin_amdgcn_sched_barrier(0);
    }

    const unsigned long long* hb =
        (const unsigned long long*)(hbuf + (size_t)(t & 1) * (NB * HID) + hoff);
    unsigned long long q0[16], q1[16];
#pragma unroll
    for (int ks = 0; ks < 16; ++ks) {
      q0[ks] = __hip_atomic_load(hb + ks * 8,     __ATOMIC_RELAXED, __HIP_MEMORY_SCOPE_AGENT);
      q1[ks] = __hip_atomic_load(hb + ks * 8 + 1, __ATOMIC_RELAXED, __HIP_MEMORY_SCOPE_AGENT);
    }
    f32x4 acc_b0 = {0.f, 0.f, 0.f, 0.f}, acc_b1 = {0.f, 0.f, 0.f, 0.f};
#pragma unroll
    for (int ks = 0; ks < 16; ks += 2) {
      union { unsigned long long q[2]; s16x8 s; } ua, ub;
      ua.q[0] = q0[ks];     ua.q[1] = q1[ks];
      ub.q[0] = q0[ks + 1]; ub.q[1] = q1[ks + 1];
      acc_b0 = __builtin_amdgcn_mfma_f32_16x16x32_bf16(ua.s, wb[ks],     acc_b0, 0, 0, 0);
      acc_b1 = __builtin_amdgcn_mfma_f32_16x16x32_bf16(ub.s, wb[ks + 1], acc_b1, 0, 0, 0);
    }
    f32x4 acc_b = acc_b0 + acc_b1;

    float (*xc)[16][16] = xch[t & 1];
    if (g == 0)      { f32x4 s = acc_a + acc_b; *(f32x4*)&xc[0][ln][kg * 4] = s; }
    else if (g == 1) { f32x4 s = acc_a + acc_b; *(f32x4*)&xc[1][ln][kg * 4] = s; }
    else             { *(f32x4*)&xc[2][ln][kg * 4] = acc_a;
                       *(f32x4*)&xc[3][ln][kg * 4] = acc_b; }
    __syncthreads();
    f32x4 Sr  = *(const f32x4*)&xc[0][ln][kg * 4];
    f32x4 Sz  = *(const f32x4*)&xc[1][ln][kg * 4];
    f32x4 Snx = *(const f32x4*)&xc[2][ln][kg * 4];
    f32x4 Snh = *(const f32x4*)&xc[3][ln][kg * 4];

    float hnew[4];
#pragma unroll
    for (int i = 0; i < 4; ++i) {
      float r = 1.f / (1.f + __expf(-Sr[i]));
      float z = 1.f / (1.f + __expf(-Sz[i]));
      float pre = Snx[i] + r * (Snh[i] + bn);
      float e = __expf(2.f * pre);
      float n = 1.f - 2.f / (e + 1.f);
      hnew[i] = n + z * (hold[i] - n);
      hold[i] = hnew[i];
    }

    if (t == TLEN - 1) {
      if (g == 0) {
#pragma unroll
        for (int i = 0; i < 4; ++i)
          out[(size_t)(b0 + kg * 4 + i) * HID + u0 + ln] = hnew[i];
      }
    } else {
      if (g == 0) {
        unsigned short* hbn = hbuf + (size_t)((t + 1) & 1) * (NB * HID);
#pragma unroll
        for (int i = 0; i < 4; ++i) {
          int v  = (int)f2bf(hnew[i]);
          int o1 = __shfl_xor(v, 1);
          unsigned int p = (unsigned int)(v & 0xffff) | ((unsigned int)(o1 & 0xffff) << 16);
          unsigned int o2 = (unsigned int)__shfl_xor((int)p, 2);
          if ((ln & 3) == 0) {
            unsigned long long q = (unsigned long long)p | ((unsigned long long)o2 << 32);
            __hip_atomic_store(
                (unsigned long long*)(hbn + (size_t)(b0 + kg * 4 + i) * HID + u0 + ln),
                q, __ATOMIC_RELAXED, __HIP_MEMORY_SCOPE_AGENT);
          }
        }
        asm volatile("s_waitcnt vmcnt(0)" ::: "memory");
        if (tid == 0)
          __hip_atomic_store(&flags[bgrp * UGRPS + ugrp], (unsigned)(t + 1),
                             __ATOMIC_RELAXED, __HIP_MEMORY_SCOPE_AGENT);
      }

      acc_a = (f32x4){bv, bv, bv, bv};
      const float* xp = xrow + (size_t)(t + 1) * INPUT;
#pragma unroll
      for (int ks = 0; ks < 16; ++ks) {
        s16x8 xa = cvt8(xp + ks * 32);
        acc_a = __builtin_amdgcn_mfma_f32_16x16x32_bf16(xa, wa[ks], acc_a, 0, 0, 0);
      }
    }
  }
}

extern "C" void kernel_launch(void* const* d_in, const int* in_sizes, int n_in,
                              void* d_out, int out_size, void* d_ws, size_t ws_size,
                              hipStream_t stream) {
  const float* xs     = (const float*)d_in[0];
  const float* wih    = (const float*)d_in[1];
  const float* whh    = (const float*)d_in[2];
  const float* bias   = (const float*)d_in[3];
  const float* bias_n = (const float*)d_in[4];
  float* out = (float*)d_out;

  const size_t tag_bytes = (size_t)2 * NB * HID * sizeof(unsigned int);   // 512 KB

  if (ws_size >= tag_bytes) {
    hipMemsetAsync(d_ws, 0, tag_bytes, stream);
    gru_tagged<<<dim3(BGRPS * UGRPS), dim3(192), 0, stream>>>(
        xs, wih, whh, bias, bias_n, out, (unsigned int*)d_ws);
  } else {
    const size_t hbuf_bytes = (size_t)2 * NB * HID * sizeof(unsigned short); // 256 KB
    const size_t flg_bytes  = (size_t)BGRPS * UGRPS * sizeof(unsigned int);  // 1 KB
    unsigned short* hbuf  = (unsigned short*)d_ws;
    unsigned int*   flags = (unsigned int*)((char*)d_ws + hbuf_bytes);
    hipMemsetAsync(d_ws, 0, hbuf_bytes + flg_bytes, stream);
    gru_flag<<<dim3(BGRPS * UGRPS), dim3(192), 0, stream>>>(
        xs, wih, whh, bias, bias_n, out, hbuf, flags);
  }
}